// Round 1
// baseline (139.798 us; speedup 1.0000x reference)
//
#include <hip/hip_runtime.h>
#include <hip/hip_bf16.h>
#include <math.h>

// NT-Xent loss, fused flash-style. N=8192 rows, D=256.
//   k_norm: row L2-normalize fp32 -> bf16 (ws); zero sumexp + out
//   k_sim : bf16 MFMA, exp((sim-1)/T) in-register, per-row sum atomics
//   k_nll : exact fp32 pos dot + per-row nll + mean via atomicAdd
//
// Register-budget history:
//   R1: 64x64 wave tile @ (256,2): spill -> 24 MB scratch, 77 us.
//   R2: 32x64 tile @ (256,3): budget 168 < ~230 demand -> spill, 82 us.
//   R3: 32x64 tile @ (256,2): no spill, k_sim 49 us. MfmaUtil 26%, all pipes
//       <27% -> barrier/latency-bound: 2x __syncthreads per jt drains
//       vmcnt(0), so the B-tile DMA only overlapped the exp epilogue.
//   R4 (this): double-buffered LDS (2x32 KB) + guide's minimum 2-phase
//       schedule: STAGE(jt+1) issued BEFORE compute(jt); one raw s_barrier
//       per tile, vmcnt(0) drain satisfied by then (DMA had the whole
//       compute phase to land). 5 barriers total vs 8, no cold drains.
#define N_ROWS 8192
#define D_DIM  256
#define HALF_N 4096
#define INV_T      14.285714285714286f      // 1/0.07
#define SCALE_LOG2 20.609929155556620f      // log2(e)/0.07
#define NEG_SCALE  -20.609929155556620f
#define EPSV   1e-8f

typedef __attribute__((ext_vector_type(8))) short bf16x8;   // 8 bf16 = 4 VGPR
typedef __attribute__((ext_vector_type(4))) float f32x4;

#define AS1 __attribute__((address_space(1)))
#define AS3 __attribute__((address_space(3)))

__device__ inline unsigned short f2bf(float x) {
    unsigned int u = __float_as_uint(x);
    unsigned int r = (u + 0x7fffu + ((u >> 16) & 1u)) >> 16;   // RNE
    return (unsigned short)r;
}

// ---------------- kernel 1: normalize rows, emit bf16; zero accumulators ---
__global__ __launch_bounds__(256) void k_norm(const float* __restrict__ feat,
                                              unsigned short* __restrict__ fbf,
                                              float* __restrict__ sumexp,
                                              float* __restrict__ out) {
    const int tid = threadIdx.x;
    const int gid = blockIdx.x * 256 + tid;
    if (gid < N_ROWS) sumexp[gid] = 0.f;
    if (gid == 0) out[0] = 0.f;

    const int w = tid >> 6, lane = tid & 63;
    const int row = blockIdx.x * 4 + w;              // 2048 blocks * 4 rows
    const float4 v = ((const float4*)(feat + row * D_DIM))[lane];
    float ss = v.x*v.x + v.y*v.y + v.z*v.z + v.w*v.w;
    #pragma unroll
    for (int off = 32; off; off >>= 1) ss += __shfl_xor(ss, off);
    const float scale = 1.f / fmaxf(sqrtf(ss), EPSV);
    ushort4 o;
    o.x = f2bf(v.x * scale);
    o.y = f2bf(v.y * scale);
    o.z = f2bf(v.z * scale);
    o.w = f2bf(v.w * scale);
    ((ushort4*)(fbf + row * D_DIM))[lane] = o;
}

// ---------------- kernel 2: fused sim + exp + row-sum ----------------------
// grid = 2048: rt = blockIdx>>5 (64 row tiles of 128), cs = blockIdx&31
// (256-col slice). 4 waves, each owns 32 rows of the 128-row block tile.
// Per jt (4 iters): B tile 64 cols x 256 k = 32 KB LDS via global_load_lds
// w=16, XOR-16B-chunk swizzle -> bank-quad-uniform ds_read_b128 frag reads.
// R4 schedule (double buffer): per jt, STAGE(jt+1 -> Bs[(jt+1)&1]) is issued
// first, then compute+epilogue on Bs[jt&1], then a single
// {s_waitcnt vmcnt(0); s_barrier} — the drain is nearly free because the
// just-issued DMA had the full compute phase (~2.5K cyc) in flight.
__global__ __launch_bounds__(256, 2) void k_sim(const unsigned short* __restrict__ fbf,
                                                float* __restrict__ sumexp) {
    __shared__ __align__(16) char Bs[2][32768];      // 64 KB; 2 blocks/CU = 128/160 KB
    const int tid  = threadIdx.x;
    const int lane = tid & 63;
    const int w    = tid >> 6;
    const int q    = lane >> 4, l15 = lane & 15;
    const int rt = blockIdx.x >> 5, cs = blockIdx.x & 31;
    const int rowBase = rt * 128 + w * 32;
    const char* Bgbase = (const char*)fbf + (size_t)(cs * 256) * (D_DIM * 2);

    // --- STAGE tile jt=0 into Bs[0] ---
    #pragma unroll
    for (int i = 0; i < 8; ++i) {                  // 8 x 4 KB = 32 KB
        const int idx = i * 256 + tid;             // 16B chunk 0..2047
        const int col = idx >> 5;
        const int cir = idx & 31;
        __builtin_amdgcn_global_load_lds(
            (const AS1 void*)(Bgbase + col * 512 + ((cir ^ (col & 7)) << 4)),
            (AS3 void*)(&Bs[0][0] + idx * 16), 16, 0, 0);
    }

    // A fragments: rows rowBase + ri*16 + l15, k = t*32 + q*8 + j
    bf16x8 afrag[8][2];
    #pragma unroll
    for (int t = 0; t < 8; ++t)
        #pragma unroll
        for (int ri = 0; ri < 2; ++ri)
            afrag[t][ri] = *(const bf16x8*)(fbf + (rowBase + ri*16 + l15) * D_DIM
                                                + t*32 + q*8);

    float rsum[2][4];
    #pragma unroll
    for (int ri = 0; ri < 2; ++ri)
        #pragma unroll
        for (int r = 0; r < 4; ++r) rsum[ri][r] = 0.f;

    // prologue sync: tile 0 resident for everyone (also drains afrag loads)
    asm volatile("s_waitcnt vmcnt(0)" ::: "memory");
    __builtin_amdgcn_s_barrier();
    asm volatile("" ::: "memory");                 // no ds_read hoist above barrier

    #pragma unroll 1                               // keep DMA live ranges tight
    for (int jt = 0; jt < 4; ++jt) {
        const char* Bp = &Bs[jt & 1][0];
        const int colBase = cs * 256 + jt * 64;

        // STAGE tile jt+1 into the other buffer; overlaps ALL of compute(jt).
        // Safe: readers of Bs[(jt+1)&1] finished before the barrier that
        // ended iteration jt-1.
        if (jt < 3) {
            const char* Bg = Bgbase + (size_t)(jt + 1) * (64 * 512);
            char* Bd = &Bs[(jt + 1) & 1][0];
            #pragma unroll
            for (int i = 0; i < 8; ++i) {
                const int idx = i * 256 + tid;
                const int col = idx >> 5;
                const int cir = idx & 31;
                __builtin_amdgcn_global_load_lds(
                    (const AS1 void*)(Bg + col * 512 + ((cir ^ (col & 7)) << 4)),
                    (AS3 void*)(Bd + idx * 16), 16, 0, 0);
            }
        }

        f32x4 acc[2][4];
        #pragma unroll
        for (int ri = 0; ri < 2; ++ri)
            #pragma unroll
            for (int ci = 0; ci < 4; ++ci) acc[ri][ci] = (f32x4){0.f, 0.f, 0.f, 0.f};

        #pragma unroll
        for (int t = 0; t < 8; ++t) {
            bf16x8 bfrag[4];
            #pragma unroll
            for (int ci = 0; ci < 4; ++ci) {
                const int c   = ci * 16 + l15;     // local col 0..63
                const int cir = t * 4 + q;         // k-chunk
                bfrag[ci] = *(const bf16x8*)(Bp + c * 512 + ((cir ^ (c & 7)) << 4));
            }
            #pragma unroll
            for (int ri = 0; ri < 2; ++ri)
                #pragma unroll
                for (int ci = 0; ci < 4; ++ci)
                    acc[ri][ci] = __builtin_amdgcn_mfma_f32_16x16x32_bf16(
                        afrag[t][ri], bfrag[ci], acc[ri][ci], 0, 0, 0);
        }

        // epilogue: e = exp2(acc*S - S); diagonal zeroed; per-row accumulate.
        // C/D layout: col=l15, row=q*4+reg. Diagonal test is per-16x16-tile
        // wave-uniform -> branch, not per-element cndmask.
        #pragma unroll
        for (int ri = 0; ri < 2; ++ri) {
            const int trow = rowBase + ri * 16;
            #pragma unroll
            for (int ci = 0; ci < 4; ++ci) {
                const int tcol = colBase + ci * 16;
                if (trow == tcol) {                // diagonal tile (rare)
                    #pragma unroll
                    for (int r = 0; r < 4; ++r) {
                        const float e = __builtin_amdgcn_exp2f(
                            __builtin_fmaf(acc[ri][ci][r], SCALE_LOG2, NEG_SCALE));
                        rsum[ri][r] += (q * 4 + r == l15) ? 0.f : e;
                    }
                } else {
                    #pragma unroll
                    for (int r = 0; r < 4; ++r)
                        rsum[ri][r] += __builtin_amdgcn_exp2f(
                            __builtin_fmaf(acc[ri][ci][r], SCALE_LOG2, NEG_SCALE));
                }
            }
        }

        // single sync per tile: my STAGE(jt+1) retired (had full compute to
        // fly) + everyone done; next iteration may read Bs[(jt+1)&1] and
        // overwrite Bs[jt&1].
        if (jt < 3) {
            asm volatile("s_waitcnt vmcnt(0)" ::: "memory");
            __builtin_amdgcn_s_barrier();
            asm volatile("" ::: "memory");
        }
    }

    // reduce across the 16 lanes of each quad (cols), then atomics (4/row-grp)
    #pragma unroll
    for (int ri = 0; ri < 2; ++ri)
        #pragma unroll
        for (int r = 0; r < 4; ++r) {
            float s = rsum[ri][r];
            s += __shfl_xor(s, 1);
            s += __shfl_xor(s, 2);
            s += __shfl_xor(s, 4);
            s += __shfl_xor(s, 8);
            if (l15 == 0)
                atomicAdd(&sumexp[rowBase + ri * 16 + q * 4 + r], s);
        }
}

// ---------------- kernel 3: exact pos similarity + nll + mean --------------
__global__ __launch_bounds__(256) void k_nll(const float* __restrict__ feat,
                                             const float* __restrict__ sumexp,
                                             float* __restrict__ out) {
    __shared__ float red[4];
    const int tid = threadIdx.x, w = tid >> 6, lane = tid & 63;
    const int i  = blockIdx.x * 4 + w;
    const int pc = (i + HALF_N) & (N_ROWS - 1);
    const float4 a = ((const float4*)(feat + i  * D_DIM))[lane];
    const float4 b = ((const float4*)(feat + pc * D_DIM))[lane];
    float dab = a.x*b.x + a.y*b.y + a.z*b.z + a.w*b.w;
    float daa = a.x*a.x + a.y*a.y + a.z*a.z + a.w*a.w;
    float dbb = b.x*b.x + b.y*b.y + b.z*b.z + b.w*b.w;
    #pragma unroll
    for (int off = 32; off; off >>= 1) {
        dab += __shfl_xor(dab, off);
        daa += __shfl_xor(daa, off);
        dbb += __shfl_xor(dbb, off);
    }
    if (lane == 0) {
        const float pos = dab / (fmaxf(sqrtf(daa), EPSV) * fmaxf(sqrtf(dbb), EPSV));
        red[w] = INV_T + logf(sumexp[i]) - pos * INV_T;
    }
    __syncthreads();
    if (tid == 0)
        atomicAdd(out, (red[0] + red[1] + red[2] + red[3]) * (1.f / N_ROWS));
}

extern "C" void kernel_launch(void* const* d_in, const int* in_sizes, int n_in,
                              void* d_out, int out_size, void* d_ws, size_t ws_size,
                              hipStream_t stream) {
    const float* feat = (const float*)d_in[0];
    char* ws = (char*)d_ws;
    unsigned short* fbf = (unsigned short*)ws;                 // 4 MB bf16
    float* sumexp = (float*)(ws + 4u * 1024u * 1024u);         // 32 KB

    k_norm<<<N_ROWS / 4, 256, 0, stream>>>(feat, fbf, sumexp, (float*)d_out);
    k_sim <<<2048,       256, 0, stream>>>(fbf, sumexp);
    k_nll <<<N_ROWS / 4, 256, 0, stream>>>(feat, sumexp, (float*)d_out);
}

// Round 2
// 129.965 us; speedup vs baseline: 1.0757x; 1.0757x over previous
//
#include <hip/hip_runtime.h>
#include <hip/hip_bf16.h>
#include <math.h>

// NT-Xent loss, fused flash-style. N=8192 rows, D=256.
//   k_norm: row L2-normalize fp32 -> bf16 (ws); zero sumexp + out
//   k_sim : bf16 MFMA, exp((sim-1)/T) in-register, per-row sum atomics
//   k_nll : exact fp32 pos dot + per-row nll + mean via atomicAdd
//
// History:
//   R1: 64x64 wave tile @ (256,2): acc[4][4]+A[128] ~280 demand -> spill, 77 us.
//   R2: 32x64 tile @ (256,3): budget 168 < ~230 demand -> spill, 82 us.
//   R3: 32x64 tile @ (256,2): no spill, k_sim 49 us. Pipes near-serialized:
//       MFMA 13 us + VALU 13 us + LDS-read 15.6 us ~= 42 ~= measured.
//   R4: LDS double-buffer: REGRESSED 57 us. Alternating Bs base defeated
//       address hoisting (+VALU) and DMA writes contended with ds_reads.
//   R5 (this): attack the largest pipe, LDS reads. Traffic law:
//       B-LDS-bytes = N^2*D*2 / rows_per_wave. Go 32 -> 64 rows/wave
//       (halves LDS to ~7.8 us, MFMA:ds_read 2:1 -> 4:1). Fit registers by
//       shrinking jt col-tile 64->32: afrag 128 + acc[4][2] 32 + rsum 16
//       + bfrag 8 ~= 215 < 256 @ 2 waves/SIMD. Single 16 KB LDS buffer,
//       R3's proven schedule (loop-invariant addresses stay hoisted).
#define N_ROWS 8192
#define D_DIM  256
#define HALF_N 4096
#define INV_T      14.285714285714286f      // 1/0.07
#define SCALE_LOG2 20.609929155556620f      // log2(e)/0.07
#define NEG_SCALE  -20.609929155556620f
#define EPSV   1e-8f

typedef __attribute__((ext_vector_type(8))) short bf16x8;   // 8 bf16 = 4 VGPR
typedef __attribute__((ext_vector_type(4))) float f32x4;

#define AS1 __attribute__((address_space(1)))
#define AS3 __attribute__((address_space(3)))

__device__ inline unsigned short f2bf(float x) {
    unsigned int u = __float_as_uint(x);
    unsigned int r = (u + 0x7fffu + ((u >> 16) & 1u)) >> 16;   // RNE
    return (unsigned short)r;
}

// ---------------- kernel 1: normalize rows, emit bf16; zero accumulators ---
__global__ __launch_bounds__(256) void k_norm(const float* __restrict__ feat,
                                              unsigned short* __restrict__ fbf,
                                              float* __restrict__ sumexp,
                                              float* __restrict__ out) {
    const int tid = threadIdx.x;
    const int gid = blockIdx.x * 256 + tid;
    if (gid < N_ROWS) sumexp[gid] = 0.f;
    if (gid == 0) out[0] = 0.f;

    const int w = tid >> 6, lane = tid & 63;
    const int row = blockIdx.x * 4 + w;              // 2048 blocks * 4 rows
    const float4 v = ((const float4*)(feat + row * D_DIM))[lane];
    float ss = v.x*v.x + v.y*v.y + v.z*v.z + v.w*v.w;
    #pragma unroll
    for (int off = 32; off; off >>= 1) ss += __shfl_xor(ss, off);
    const float scale = 1.f / fmaxf(sqrtf(ss), EPSV);
    ushort4 o;
    o.x = f2bf(v.x * scale);
    o.y = f2bf(v.y * scale);
    o.z = f2bf(v.z * scale);
    o.w = f2bf(v.w * scale);
    ((ushort4*)(fbf + row * D_DIM))[lane] = o;
}

// ---------------- kernel 2: fused sim + exp + row-sum ----------------------
// grid = 1024: rt = blockIdx>>5 (32 row tiles of 256), cs = blockIdx&31
// (256-col slice). 4 waves, each owns 64 rows of the 256-row block tile.
// Per jt (8 iters): B tile 32 cols x 256 k = 16 KB LDS via global_load_lds
// w=16, XOR-16B-chunk swizzle -> bank-quad-uniform ds_read_b128 frag reads.
// A (64 rows x 256 k) held entirely in regs: 128 VGPR. Per wave per jt:
// 16 ds_read_b128 + 64 MFMA (4:1) + 32-exp epilogue. DMA for jt+1 issued
// before the epilogue (R3 schedule; Bs base constant -> addresses hoisted).
__global__ __launch_bounds__(256, 2) void k_sim(const unsigned short* __restrict__ fbf,
                                                float* __restrict__ sumexp) {
    __shared__ __align__(16) char Bs[16384];
    const int tid  = threadIdx.x;
    const int lane = tid & 63;
    const int w    = tid >> 6;
    const int q    = lane >> 4, l15 = lane & 15;
    const int rt = blockIdx.x >> 5, cs = blockIdx.x & 31;
    const int rowBase = rt * 256 + w * 64;
    const char* Bgbase = (const char*)fbf + (size_t)(cs * 256) * (D_DIM * 2);

    // --- issue DMA for jt=0 while afrag loads are in flight ---
    #pragma unroll
    for (int i = 0; i < 4; ++i) {                  // 4 x 4 KB = 16 KB
        const int idx = i * 256 + tid;             // 16B chunk 0..1023
        const int col = idx >> 5;                  // 0..31
        const int cir = idx & 31;
        __builtin_amdgcn_global_load_lds(
            (const AS1 void*)(Bgbase + col * 512 + ((cir ^ (col & 7)) << 4)),
            (AS3 void*)(Bs + idx * 16), 16, 0, 0);
    }

    // A fragments: rows rowBase + ri*16 + l15, k = t*32 + q*8 + j  (128 VGPR)
    bf16x8 afrag[8][4];
    #pragma unroll
    for (int t = 0; t < 8; ++t)
        #pragma unroll
        for (int ri = 0; ri < 4; ++ri)
            afrag[t][ri] = *(const bf16x8*)(fbf + (rowBase + ri*16 + l15) * D_DIM
                                                + t*32 + q*8);

    float rsum[4][4];
    #pragma unroll
    for (int ri = 0; ri < 4; ++ri)
        #pragma unroll
        for (int r = 0; r < 4; ++r) rsum[ri][r] = 0.f;

    #pragma unroll 1                               // keep DMA live ranges tight
    for (int jt = 0; jt < 8; ++jt) {
        const int colBase = cs * 256 + jt * 32;

        __syncthreads();                           // DMA of tile jt drained

        f32x4 acc[4][2];
        #pragma unroll
        for (int ri = 0; ri < 4; ++ri)
            #pragma unroll
            for (int ci = 0; ci < 2; ++ci) acc[ri][ci] = (f32x4){0.f, 0.f, 0.f, 0.f};

        #pragma unroll
        for (int t = 0; t < 8; ++t) {
            bf16x8 bfrag[2];
            #pragma unroll
            for (int ci = 0; ci < 2; ++ci) {
                const int c   = ci * 16 + l15;     // local col 0..31
                const int cir = t * 4 + q;         // k-chunk
                bfrag[ci] = *(const bf16x8*)(Bs + c * 512 + ((cir ^ (c & 7)) << 4));
            }
            #pragma unroll
            for (int ri = 0; ri < 4; ++ri)
                #pragma unroll
                for (int ci = 0; ci < 2; ++ci)
                    acc[ri][ci] = __builtin_amdgcn_mfma_f32_16x16x32_bf16(
                        afrag[t][ri], bfrag[ci], acc[ri][ci], 0, 0, 0);
        }

        // B tile consumed; start DMA for jt+1 so it overlaps the exp epilogue
        if (jt < 7) {
            __syncthreads();                       // all waves done reading Bs
            const char* Bg = Bgbase + (size_t)(jt + 1) * (32 * 512);
            #pragma unroll
            for (int i = 0; i < 4; ++i) {
                const int idx = i * 256 + tid;
                const int col = idx >> 5;
                const int cir = idx & 31;
                __builtin_amdgcn_global_load_lds(
                    (const AS1 void*)(Bg + col * 512 + ((cir ^ (col & 7)) << 4)),
                    (AS3 void*)(Bs + idx * 16), 16, 0, 0);
            }
        }

        // epilogue: e = exp2(acc*S - S); diagonal zeroed; per-row accumulate.
        // C/D layout: col=l15, row=q*4+reg. Diagonal test is per-16x16-tile
        // wave-uniform -> branch, not per-element cndmask.
        #pragma unroll
        for (int ri = 0; ri < 4; ++ri) {
            const int trow = rowBase + ri * 16;
            #pragma unroll
            for (int ci = 0; ci < 2; ++ci) {
                const int tcol = colBase + ci * 16;
                if (trow == tcol) {                // diagonal tile (rare)
                    #pragma unroll
                    for (int r = 0; r < 4; ++r) {
                        const float e = __builtin_amdgcn_exp2f(
                            __builtin_fmaf(acc[ri][ci][r], SCALE_LOG2, NEG_SCALE));
                        rsum[ri][r] += (q * 4 + r == l15) ? 0.f : e;
                    }
                } else {
                    #pragma unroll
                    for (int r = 0; r < 4; ++r)
                        rsum[ri][r] += __builtin_amdgcn_exp2f(
                            __builtin_fmaf(acc[ri][ci][r], SCALE_LOG2, NEG_SCALE));
                }
            }
        }
    }

    // reduce across the 16 lanes of each quad (cols), then atomics (4/row-grp)
    #pragma unroll
    for (int ri = 0; ri < 4; ++ri)
        #pragma unroll
        for (int r = 0; r < 4; ++r) {
            float s = rsum[ri][r];
            s += __shfl_xor(s, 1);
            s += __shfl_xor(s, 2);
            s += __shfl_xor(s, 4);
            s += __shfl_xor(s, 8);
            if (l15 == 0)
                atomicAdd(&sumexp[rowBase + ri * 16 + q * 4 + r], s);
        }
}

// ---------------- kernel 3: exact pos similarity + nll + mean --------------
__global__ __launch_bounds__(256) void k_nll(const float* __restrict__ feat,
                                             const float* __restrict__ sumexp,
                                             float* __restrict__ out) {
    __shared__ float red[4];
    const int tid = threadIdx.x, w = tid >> 6, lane = tid & 63;
    const int i  = blockIdx.x * 4 + w;
    const int pc = (i + HALF_N) & (N_ROWS - 1);
    const float4 a = ((const float4*)(feat + i  * D_DIM))[lane];
    const float4 b = ((const float4*)(feat + pc * D_DIM))[lane];
    float dab = a.x*b.x + a.y*b.y + a.z*b.z + a.w*b.w;
    float daa = a.x*a.x + a.y*a.y + a.z*a.z + a.w*a.w;
    float dbb = b.x*b.x + b.y*b.y + b.z*b.z + b.w*b.w;
    #pragma unroll
    for (int off = 32; off; off >>= 1) {
        dab += __shfl_xor(dab, off);
        daa += __shfl_xor(daa, off);
        dbb += __shfl_xor(dbb, off);
    }
    if (lane == 0) {
        const float pos = dab / (fmaxf(sqrtf(daa), EPSV) * fmaxf(sqrtf(dbb), EPSV));
        red[w] = INV_T + logf(sumexp[i]) - pos * INV_T;
    }
    __syncthreads();
    if (tid == 0)
        atomicAdd(out, (red[0] + red[1] + red[2] + red[3]) * (1.f / N_ROWS));
}

extern "C" void kernel_launch(void* const* d_in, const int* in_sizes, int n_in,
                              void* d_out, int out_size, void* d_ws, size_t ws_size,
                              hipStream_t stream) {
    const float* feat = (const float*)d_in[0];
    char* ws = (char*)d_ws;
    unsigned short* fbf = (unsigned short*)ws;                 // 4 MB bf16
    float* sumexp = (float*)(ws + 4u * 1024u * 1024u);         // 32 KB

    k_norm<<<N_ROWS / 4, 256, 0, stream>>>(feat, fbf, sumexp, (float*)d_out);
    k_sim <<<1024,       256, 0, stream>>>(fbf, sumexp);
    k_nll <<<N_ROWS / 4, 256, 0, stream>>>(feat, sumexp, (float*)d_out);
}

// Round 3
// 124.962 us; speedup vs baseline: 1.1187x; 1.0400x over previous
//
#include <hip/hip_runtime.h>
#include <hip/hip_bf16.h>
#include <math.h>

// NT-Xent loss, fused flash-style. N=8192 rows, D=256.
//   k_norm: row L2-normalize fp32 -> bf16 (ws); zero sumexp + out
//   k_sim : bf16 MFMA, exp((sim-1)/T) in-register, row+col sums via symmetry
//   k_nll : exact fp32 pos dot + per-row nll + mean via atomicAdd
//
// History:
//   R1: 64x64 wave tile @ (256,2): ~280 demand -> spill, 77 us.
//   R2: 32x64 tile @ (256,3): budget 168 < demand -> spill, 82 us.
//   R3: 32x64 tile @ (256,2): no spill, k_sim 49.3 us.
//   R4: LDS double-buffer: REGRESSED 57 us (addr rehoisting + DMA/ds port
//       contention). Lesson: scheduling tweaks at 2 waves/SIMD don't pay.
//   R5: 64 rows/wave (halved LDS reads, conflicts 4.19M->2.10M): only -2 us
//       (47.2). Pipes sum to ~20 us serialized; measured 47 -> the kernel is
//       STALL-dominated. Shaving one pipe doesn't move the total.
//   R6 (this): cut the WORK. exp(sim) is symmetric -> row sums == col sums.
//       Compute only upper-triangle block tiles (rt >= cs): 496 off-diag
//       blocks contribute row sums AND (transposed) col sums; 32 diagonal
//       blocks computed fully with diag mask. Work = 51.6% of R5 across
//       every pipe AND every stall (half the barrier periods). Per-element
//       math identical to R5; only summation order changes.
#define N_ROWS 8192
#define D_DIM  256
#define HALF_N 4096
#define INV_T      14.285714285714286f      // 1/0.07
#define SCALE_LOG2 20.609929155556620f      // log2(e)/0.07
#define NEG_SCALE  -20.609929155556620f
#define EPSV   1e-8f

typedef __attribute__((ext_vector_type(8))) short bf16x8;   // 8 bf16 = 4 VGPR
typedef __attribute__((ext_vector_type(4))) float f32x4;

#define AS1 __attribute__((address_space(1)))
#define AS3 __attribute__((address_space(3)))

__device__ inline unsigned short f2bf(float x) {
    unsigned int u = __float_as_uint(x);
    unsigned int r = (u + 0x7fffu + ((u >> 16) & 1u)) >> 16;   // RNE
    return (unsigned short)r;
}

// ---------------- kernel 1: normalize rows, emit bf16; zero accumulators ---
__global__ __launch_bounds__(256) void k_norm(const float* __restrict__ feat,
                                              unsigned short* __restrict__ fbf,
                                              float* __restrict__ sumexp,
                                              float* __restrict__ out) {
    const int tid = threadIdx.x;
    const int gid = blockIdx.x * 256 + tid;
    if (gid < N_ROWS) sumexp[gid] = 0.f;
    if (gid == 0) out[0] = 0.f;

    const int w = tid >> 6, lane = tid & 63;
    const int row = blockIdx.x * 4 + w;              // 2048 blocks * 4 rows
    const float4 v = ((const float4*)(feat + row * D_DIM))[lane];
    float ss = v.x*v.x + v.y*v.y + v.z*v.z + v.w*v.w;
    #pragma unroll
    for (int off = 32; off; off >>= 1) ss += __shfl_xor(ss, off);
    const float scale = 1.f / fmaxf(sqrtf(ss), EPSV);
    ushort4 o;
    o.x = f2bf(v.x * scale);
    o.y = f2bf(v.y * scale);
    o.z = f2bf(v.z * scale);
    o.w = f2bf(v.w * scale);
    ((ushort4*)(fbf + row * D_DIM))[lane] = o;
}

// ---------------- kernel 2: fused sim + exp + row/col-sum (symmetric) ------
// grid = 528 upper-triangle block pairs (rt,cs), rt >= cs, of 256x256.
// 4 waves, each owns 64 rows (A entirely in regs: 128 VGPR). Per jt (8):
// B tile 32 cols x 256 k = 16 KB LDS via global_load_lds w=16, XOR-16B-chunk
// swizzle -> bank-quad-uniform ds_read_b128. 16 ds_read + 64 MFMA per wave
// per jt; DMA for jt+1 issued before the exp epilogue (R3/R5 schedule).
// Off-diag blocks: e[r][c] feeds rsum[r] (register) AND csum[c] (per-jt
// shfl-reduce over q + atomicAdd) — by symmetry csum[c] is row c's sum over
// this block's rows. Diag blocks (32): full 256x256, row sums only, diag
// masked per element.
__global__ __launch_bounds__(256, 2) void k_sim(const unsigned short* __restrict__ fbf,
                                                float* __restrict__ sumexp) {
    __shared__ __align__(16) char Bs[16384];
    const int tid  = threadIdx.x;
    const int lane = tid & 63;
    const int w    = tid >> 6;
    const int q    = lane >> 4, l15 = lane & 15;

    // triangular decode: bid -> (rt, cs), rt >= cs
    const int bid = blockIdx.x;
    int rt = (int)((sqrtf(8.f * (float)bid + 1.f) - 1.f) * 0.5f);
    while ((rt + 1) * (rt + 2) / 2 <= bid) ++rt;   // fixup fp edge cases
    while (rt * (rt + 1) / 2 > bid) --rt;
    const int cs = bid - rt * (rt + 1) / 2;
    const bool isDiag = (rt == cs);

    const int rowBase = rt * 256 + w * 64;
    const char* Bgbase = (const char*)fbf + (size_t)(cs * 256) * (D_DIM * 2);

    // --- issue DMA for jt=0 while afrag loads are in flight ---
    #pragma unroll
    for (int i = 0; i < 4; ++i) {                  // 4 x 4 KB = 16 KB
        const int idx = i * 256 + tid;             // 16B chunk 0..1023
        const int col = idx >> 5;                  // 0..31
        const int cir = idx & 31;
        __builtin_amdgcn_global_load_lds(
            (const AS1 void*)(Bgbase + col * 512 + ((cir ^ (col & 7)) << 4)),
            (AS3 void*)(Bs + idx * 16), 16, 0, 0);
    }

    // A fragments: rows rowBase + ri*16 + l15, k = t*32 + q*8 + j  (128 VGPR)
    bf16x8 afrag[8][4];
    #pragma unroll
    for (int t = 0; t < 8; ++t)
        #pragma unroll
        for (int ri = 0; ri < 4; ++ri)
            afrag[t][ri] = *(const bf16x8*)(fbf + (rowBase + ri*16 + l15) * D_DIM
                                                + t*32 + q*8);

    float rsum[4][4];
    #pragma unroll
    for (int ri = 0; ri < 4; ++ri)
        #pragma unroll
        for (int r = 0; r < 4; ++r) rsum[ri][r] = 0.f;

    #pragma unroll 1                               // keep DMA live ranges tight
    for (int jt = 0; jt < 8; ++jt) {
        const int colBase = cs * 256 + jt * 32;

        __syncthreads();                           // DMA of tile jt drained

        f32x4 acc[4][2];
        #pragma unroll
        for (int ri = 0; ri < 4; ++ri)
            #pragma unroll
            for (int ci = 0; ci < 2; ++ci) acc[ri][ci] = (f32x4){0.f, 0.f, 0.f, 0.f};

        #pragma unroll
        for (int t = 0; t < 8; ++t) {
            bf16x8 bfrag[2];
            #pragma unroll
            for (int ci = 0; ci < 2; ++ci) {
                const int c   = ci * 16 + l15;     // local col 0..31
                const int cir = t * 4 + q;         // k-chunk
                bfrag[ci] = *(const bf16x8*)(Bs + c * 512 + ((cir ^ (c & 7)) << 4));
            }
            #pragma unroll
            for (int ri = 0; ri < 4; ++ri)
                #pragma unroll
                for (int ci = 0; ci < 2; ++ci)
                    acc[ri][ci] = __builtin_amdgcn_mfma_f32_16x16x32_bf16(
                        afrag[t][ri], bfrag[ci], acc[ri][ci], 0, 0, 0);
        }

        // B tile consumed; start DMA for jt+1 so it overlaps the exp epilogue
        if (jt < 7) {
            __syncthreads();                       // all waves done reading Bs
            const char* Bg = Bgbase + (size_t)(jt + 1) * (32 * 512);
            #pragma unroll
            for (int i = 0; i < 4; ++i) {
                const int idx = i * 256 + tid;
                const int col = idx >> 5;
                const int cir = idx & 31;
                __builtin_amdgcn_global_load_lds(
                    (const AS1 void*)(Bg + col * 512 + ((cir ^ (col & 7)) << 4)),
                    (AS3 void*)(Bs + idx * 16), 16, 0, 0);
            }
        }

        // epilogue: e = exp2(acc*S - S). C/D layout: col=l15, row=q*4+reg.
        if (isDiag) {
            // full 256x256 diagonal block: row sums only, mask true diagonal
            #pragma unroll
            for (int ri = 0; ri < 4; ++ri) {
                const int trow = rowBase + ri * 16;
                #pragma unroll
                for (int ci = 0; ci < 2; ++ci) {
                    const int tcol = colBase + ci * 16;
                    if (trow == tcol) {            // diagonal 16x16 tile
                        #pragma unroll
                        for (int r = 0; r < 4; ++r) {
                            const float e = __builtin_amdgcn_exp2f(
                                __builtin_fmaf(acc[ri][ci][r], SCALE_LOG2, NEG_SCALE));
                            rsum[ri][r] += (q * 4 + r == l15) ? 0.f : e;
                        }
                    } else {
                        #pragma unroll
                        for (int r = 0; r < 4; ++r)
                            rsum[ri][r] += __builtin_amdgcn_exp2f(
                                __builtin_fmaf(acc[ri][ci][r], SCALE_LOG2, NEG_SCALE));
                    }
                }
            }
        } else {
            // off-diagonal (rt > cs): rsum for rows AND csum for cols
            float csum0 = 0.f, csum1 = 0.f;
            #pragma unroll
            for (int ri = 0; ri < 4; ++ri) {
                #pragma unroll
                for (int r = 0; r < 4; ++r) {
                    const float e0 = __builtin_amdgcn_exp2f(
                        __builtin_fmaf(acc[ri][0][r], SCALE_LOG2, NEG_SCALE));
                    const float e1 = __builtin_amdgcn_exp2f(
                        __builtin_fmaf(acc[ri][1][r], SCALE_LOG2, NEG_SCALE));
                    rsum[ri][r] += e0 + e1;
                    csum0 += e0;
                    csum1 += e1;
                }
            }
            // reduce csum over the 4 q-groups (rows live across q-lanes)
            csum0 += __shfl_xor(csum0, 16); csum0 += __shfl_xor(csum0, 32);
            csum1 += __shfl_xor(csum1, 16); csum1 += __shfl_xor(csum1, 32);
            if (q == 0)      atomicAdd(&sumexp[colBase      + l15], csum0);
            else if (q == 1) atomicAdd(&sumexp[colBase + 16 + l15], csum1);
        }
    }

    // reduce across the 16 lanes of each quad (cols), then atomics (4/row-grp)
    #pragma unroll
    for (int ri = 0; ri < 4; ++ri)
        #pragma unroll
        for (int r = 0; r < 4; ++r) {
            float s = rsum[ri][r];
            s += __shfl_xor(s, 1);
            s += __shfl_xor(s, 2);
            s += __shfl_xor(s, 4);
            s += __shfl_xor(s, 8);
            if (l15 == 0)
                atomicAdd(&sumexp[rowBase + ri * 16 + q * 4 + r], s);
        }
}

// ---------------- kernel 3: exact pos similarity + nll + mean --------------
__global__ __launch_bounds__(256) void k_nll(const float* __restrict__ feat,
                                             const float* __restrict__ sumexp,
                                             float* __restrict__ out) {
    __shared__ float red[4];
    const int tid = threadIdx.x, w = tid >> 6, lane = tid & 63;
    const int i  = blockIdx.x * 4 + w;
    const int pc = (i + HALF_N) & (N_ROWS - 1);
    const float4 a = ((const float4*)(feat + i  * D_DIM))[lane];
    const float4 b = ((const float4*)(feat + pc * D_DIM))[lane];
    float dab = a.x*b.x + a.y*b.y + a.z*b.z + a.w*b.w;
    float daa = a.x*a.x + a.y*a.y + a.z*a.z + a.w*a.w;
    float dbb = b.x*b.x + b.y*b.y + b.z*b.z + b.w*b.w;
    #pragma unroll
    for (int off = 32; off; off >>= 1) {
        dab += __shfl_xor(dab, off);
        daa += __shfl_xor(daa, off);
        dbb += __shfl_xor(dbb, off);
    }
    if (lane == 0) {
        const float pos = dab / (fmaxf(sqrtf(daa), EPSV) * fmaxf(sqrtf(dbb), EPSV));
        red[w] = INV_T + logf(sumexp[i]) - pos * INV_T;
    }
    __syncthreads();
    if (tid == 0)
        atomicAdd(out, (red[0] + red[1] + red[2] + red[3]) * (1.f / N_ROWS));
}

extern "C" void kernel_launch(void* const* d_in, const int* in_sizes, int n_in,
                              void* d_out, int out_size, void* d_ws, size_t ws_size,
                              hipStream_t stream) {
    const float* feat = (const float*)d_in[0];
    char* ws = (char*)d_ws;
    unsigned short* fbf = (unsigned short*)ws;                 // 4 MB bf16
    float* sumexp = (float*)(ws + 4u * 1024u * 1024u);         // 32 KB

    k_norm<<<N_ROWS / 4, 256, 0, stream>>>(feat, fbf, sumexp, (float*)d_out);
    k_sim <<<528,        256, 0, stream>>>(fbf, sumexp);
    k_nll <<<N_ROWS / 4, 256, 0, stream>>>(feat, sumexp, (float*)d_out);
}

// Round 4
// 124.152 us; speedup vs baseline: 1.1260x; 1.0065x over previous
//
#include <hip/hip_runtime.h>
#include <hip/hip_bf16.h>
#include <math.h>

// NT-Xent loss, fused flash-style. N=8192 rows, D=256.
//   k_norm: row L2-normalize fp32 -> bf16 (ws); zero sumexp + out
//   k_sim : bf16 MFMA, exp((sim-1)/T) in-register, row+col sums via symmetry
//   k_nll : exact fp32 pos dot + per-row nll + mean via atomicAdd
//
// History:
//   R1: 64x64 wave tile @ (256,2): ~280 demand -> spill, 77 us.
//   R2: 32x64 tile @ (256,3): budget 168 < demand -> spill, 82 us.
//   R3: 32x64 tile @ (256,2): no spill, k_sim 49.3 us.
//   R4: LDS double-buffer: REGRESSED 57 us (addr rehoisting + DMA/ds port
//       contention). Scheduling tweaks at 2 waves/SIMD don't pay.
//   R5: 64 rows/wave (halved LDS reads): only -2 us (47.2). Stall-dominated.
//   R6: symmetry (row sums == col sums), 528 upper-tri blocks: k_sim ~43,
//       total -5 only. DIAGNOSIS: 2 blocks/CU => 512 co-resident slots;
//       528 blocks = 1.03 rounds -> quantized to 2 full rounds. The 16
//       stragglers cost a whole round.
//   R7 (this): strip-balanced persistent blocks. 528 tiles x 8 jt-strips =
//       4224 strips spread contiguously over EXACTLY 512 blocks (8 or 9
//       each): single round, max tail 9/8.25 = +9%. Tile boundary inside a
//       block: flush rsum (atomicAdd) + afrag reload (issued before the exp
//       epilogue so HBM latency hides under VALU). B LDS addresses stay
//       loop-invariant; R6's per-strip DMA/barrier schedule kept verbatim.
#define N_ROWS 8192
#define D_DIM  256
#define HALF_N 4096
#define INV_T      14.285714285714286f      // 1/0.07
#define SCALE_LOG2 20.609929155556620f      // log2(e)/0.07
#define NEG_SCALE  -20.609929155556620f
#define EPSV   1e-8f

typedef __attribute__((ext_vector_type(8))) short bf16x8;   // 8 bf16 = 4 VGPR
typedef __attribute__((ext_vector_type(4))) float f32x4;

#define AS1 __attribute__((address_space(1)))
#define AS3 __attribute__((address_space(3)))

__device__ inline unsigned short f2bf(float x) {
    unsigned int u = __float_as_uint(x);
    unsigned int r = (u + 0x7fffu + ((u >> 16) & 1u)) >> 16;   // RNE
    return (unsigned short)r;
}

// ---------------- kernel 1: normalize rows, emit bf16; zero accumulators ---
__global__ __launch_bounds__(256) void k_norm(const float* __restrict__ feat,
                                              unsigned short* __restrict__ fbf,
                                              float* __restrict__ sumexp,
                                              float* __restrict__ out) {
    const int tid = threadIdx.x;
    const int gid = blockIdx.x * 256 + tid;
    if (gid < N_ROWS) sumexp[gid] = 0.f;
    if (gid == 0) out[0] = 0.f;

    const int w = tid >> 6, lane = tid & 63;
    const int row = blockIdx.x * 4 + w;              // 2048 blocks * 4 rows
    const float4 v = ((const float4*)(feat + row * D_DIM))[lane];
    float ss = v.x*v.x + v.y*v.y + v.z*v.z + v.w*v.w;
    #pragma unroll
    for (int off = 32; off; off >>= 1) ss += __shfl_xor(ss, off);
    const float scale = 1.f / fmaxf(sqrtf(ss), EPSV);
    ushort4 o;
    o.x = f2bf(v.x * scale);
    o.y = f2bf(v.y * scale);
    o.z = f2bf(v.z * scale);
    o.w = f2bf(v.w * scale);
    ((ushort4*)(fbf + row * D_DIM))[lane] = o;
}

// ---------------- kernel 2: fused sim + exp + row/col-sum (symmetric) ------
// Work unit = strip (tile tt, jt): 256 rows x 32 cols, tt over the 528
// upper-triangle 256x256 tiles (rt >= cs), jt in [0,8). 4224 strips total,
// block b owns strips [(33b)>>2, (33(b+1))>>2)  (8 or 9; spans <= 2 tiles).
// 4 waves x 64 rows; A (64x256) in regs (128 VGPR). Per strip: 16 KB B via
// global_load_lds w=16 XOR-16B-chunk swizzle (conflict-free ds_read_b128),
// 16 ds_read + 64 MFMA per wave, DMA(next strip) before the exp epilogue.
// Off-diag: rsum[r] in regs + csum[c] per strip (shfl over q + atomicAdd).
// Diag: full tile, diagonal masked, row sums only.
__global__ __launch_bounds__(256, 2) void k_sim(const unsigned short* __restrict__ fbf,
                                                float* __restrict__ sumexp) {
    __shared__ __align__(16) char Bs[16384];
    const int tid  = threadIdx.x;
    const int lane = tid & 63;
    const int w    = tid >> 6;
    const int q    = lane >> 4, l15 = lane & 15;

    int g          = (33 * blockIdx.x) >> 2;          // first strip
    const int gEnd = (33 * (blockIdx.x + 1)) >> 2;    // one past last

    // decode tile of strip g: tt -> (rt, cs), rt >= cs
    const int tt0 = g >> 3;
    int rt = (int)((sqrtf(8.f * (float)tt0 + 1.f) - 1.f) * 0.5f);
    while ((rt + 1) * (rt + 2) / 2 <= tt0) ++rt;
    while (rt * (rt + 1) / 2 > tt0) --rt;
    int cs = tt0 - rt * (rt + 1) / 2;
    int jt = g & 7;

#define STAGE(colRow0) do {                                                   \
        const char* Bg_ = (const char*)fbf + (size_t)(colRow0) * 512;         \
        _Pragma("unroll")                                                     \
        for (int i_ = 0; i_ < 4; ++i_) {                                      \
            const int idx_ = i_ * 256 + tid;                                  \
            const int col_ = idx_ >> 5;                                       \
            const int cir_ = idx_ & 31;                                       \
            __builtin_amdgcn_global_load_lds(                                 \
                (const AS1 void*)(Bg_ + col_ * 512 + ((cir_ ^ (col_ & 7)) << 4)), \
                (AS3 void*)(Bs + idx_ * 16), 16, 0, 0);                       \
        }                                                                     \
    } while (0)

    bf16x8 afrag[8][4];
#define LOAD_A(rt_) do {                                                      \
        const int rowBase_ = (rt_) * 256 + w * 64;                            \
        _Pragma("unroll")                                                     \
        for (int t_ = 0; t_ < 8; ++t_)                                        \
            _Pragma("unroll")                                                 \
            for (int ri_ = 0; ri_ < 4; ++ri_)                                 \
                afrag[t_][ri_] = *(const bf16x8*)(fbf                         \
                    + (rowBase_ + ri_*16 + l15) * D_DIM + t_*32 + q*8);       \
    } while (0)

    float rsum[4][4];
#define ZERO_RSUM() do {                                                      \
        _Pragma("unroll")                                                     \
        for (int ri_ = 0; ri_ < 4; ++ri_)                                     \
            _Pragma("unroll")                                                 \
            for (int r_ = 0; r_ < 4; ++r_) rsum[ri_][r_] = 0.f;               \
    } while (0)

    // reduce each rsum over 16 cols (lanes of the quad) and atomically flush
#define FLUSH_RSUM(rt_) do {                                                  \
        const int rowBase_ = (rt_) * 256 + w * 64;                            \
        _Pragma("unroll")                                                     \
        for (int ri_ = 0; ri_ < 4; ++ri_)                                     \
            _Pragma("unroll")                                                 \
            for (int r_ = 0; r_ < 4; ++r_) {                                  \
                float s_ = rsum[ri_][r_];                                     \
                s_ += __shfl_xor(s_, 1);                                      \
                s_ += __shfl_xor(s_, 2);                                      \
                s_ += __shfl_xor(s_, 4);                                      \
                s_ += __shfl_xor(s_, 8);                                      \
                if (l15 == 0)                                                 \
                    atomicAdd(&sumexp[rowBase_ + ri_ * 16 + q * 4 + r_], s_); \
            }                                                                 \
    } while (0)

    // prologue: DMA strip g, A for its tile
    STAGE(cs * 256 + jt * 32);
    LOAD_A(rt);
    ZERO_RSUM();

    while (true) {
        const int colBase = cs * 256 + jt * 32;
        const bool isDiag = (rt == cs);
        const int rowBase = rt * 256 + w * 64;

        __syncthreads();                           // DMA of strip g drained

        f32x4 acc[4][2];
        #pragma unroll
        for (int ri = 0; ri < 4; ++ri)
            #pragma unroll
            for (int ci = 0; ci < 2; ++ci) acc[ri][ci] = (f32x4){0.f, 0.f, 0.f, 0.f};

        #pragma unroll
        for (int t = 0; t < 8; ++t) {
            bf16x8 bfrag[2];
            #pragma unroll
            for (int ci = 0; ci < 2; ++ci) {
                const int c   = ci * 16 + l15;     // local col 0..31
                const int cir = t * 4 + q;         // k-chunk
                bfrag[ci] = *(const bf16x8*)(Bs + c * 512 + ((cir ^ (c & 7)) << 4));
            }
            #pragma unroll
            for (int ri = 0; ri < 4; ++ri)
                #pragma unroll
                for (int ci = 0; ci < 2; ++ci)
                    acc[ri][ci] = __builtin_amdgcn_mfma_f32_16x16x32_bf16(
                        afrag[t][ri], bfrag[ci], acc[ri][ci], 0, 0, 0);
        }

        // advance coordinates for strip g+1
        const bool more = (g + 1 < gEnd);
        int nrt = rt, ncs = cs, njt = jt + 1;
        if (njt == 8) {
            njt = 0; ncs = cs + 1;
            if (ncs > rt) { nrt = rt + 1; ncs = 0; }
        }

        // B consumed; DMA next strip so it overlaps the exp epilogue
        if (more) {
            __syncthreads();                       // all waves done reading Bs
            STAGE(ncs * 256 + njt * 32);
            // tile change: issue afrag reload now, latency hides under exp
            if (njt == 0) LOAD_A(nrt);
        }

        // epilogue: e = exp2(acc*S - S). C/D layout: col=l15, row=q*4+reg.
        if (isDiag) {
            #pragma unroll
            for (int ri = 0; ri < 4; ++ri) {
                const int trow = rowBase + ri * 16;
                #pragma unroll
                for (int ci = 0; ci < 2; ++ci) {
                    const int tcol = colBase + ci * 16;
                    if (trow == tcol) {            // diagonal 16x16 tile
                        #pragma unroll
                        for (int r = 0; r < 4; ++r) {
                            const float e = __builtin_amdgcn_exp2f(
                                __builtin_fmaf(acc[ri][ci][r], SCALE_LOG2, NEG_SCALE));
                            rsum[ri][r] += (q * 4 + r == l15) ? 0.f : e;
                        }
                    } else {
                        #pragma unroll
                        for (int r = 0; r < 4; ++r)
                            rsum[ri][r] += __builtin_amdgcn_exp2f(
                                __builtin_fmaf(acc[ri][ci][r], SCALE_LOG2, NEG_SCALE));
                    }
                }
            }
        } else {
            // off-diagonal (rt > cs): rsum for rows AND csum for cols
            float csum0 = 0.f, csum1 = 0.f;
            #pragma unroll
            for (int ri = 0; ri < 4; ++ri) {
                #pragma unroll
                for (int r = 0; r < 4; ++r) {
                    const float e0 = __builtin_amdgcn_exp2f(
                        __builtin_fmaf(acc[ri][0][r], SCALE_LOG2, NEG_SCALE));
                    const float e1 = __builtin_amdgcn_exp2f(
                        __builtin_fmaf(acc[ri][1][r], SCALE_LOG2, NEG_SCALE));
                    rsum[ri][r] += e0 + e1;
                    csum0 += e0;
                    csum1 += e1;
                }
            }
            // reduce csum over the 4 q-groups (block rows live across q)
            csum0 += __shfl_xor(csum0, 16); csum0 += __shfl_xor(csum0, 32);
            csum1 += __shfl_xor(csum1, 16); csum1 += __shfl_xor(csum1, 32);
            if (q == 0)      atomicAdd(&sumexp[colBase      + l15], csum0);
            else if (q == 1) atomicAdd(&sumexp[colBase + 16 + l15], csum1);
        }

        if (!more) break;
        if (njt == 0) {                            // crossed a tile boundary
            FLUSH_RSUM(rt);
            ZERO_RSUM();
        }
        rt = nrt; cs = ncs; jt = njt; ++g;
    }

    FLUSH_RSUM(rt);
#undef STAGE
#undef LOAD_A
#undef ZERO_RSUM
#undef FLUSH_RSUM
}

// ---------------- kernel 3: exact pos similarity + nll + mean --------------
__global__ __launch_bounds__(256) void k_nll(const float* __restrict__ feat,
                                             const float* __restrict__ sumexp,
                                             float* __restrict__ out) {
    __shared__ float red[4];
    const int tid = threadIdx.x, w = tid >> 6, lane = tid & 63;
    const int i  = blockIdx.x * 4 + w;
    const int pc = (i + HALF_N) & (N_ROWS - 1);
    const float4 a = ((const float4*)(feat + i  * D_DIM))[lane];
    const float4 b = ((const float4*)(feat + pc * D_DIM))[lane];
    float dab = a.x*b.x + a.y*b.y + a.z*b.z + a.w*b.w;
    float daa = a.x*a.x + a.y*a.y + a.z*a.z + a.w*a.w;
    float dbb = b.x*b.x + b.y*b.y + b.z*b.z + b.w*b.w;
    #pragma unroll
    for (int off = 32; off; off >>= 1) {
        dab += __shfl_xor(dab, off);
        daa += __shfl_xor(daa, off);
        dbb += __shfl_xor(dbb, off);
    }
    if (lane == 0) {
        const float pos = dab / (fmaxf(sqrtf(daa), EPSV) * fmaxf(sqrtf(dbb), EPSV));
        red[w] = INV_T + logf(sumexp[i]) - pos * INV_T;
    }
    __syncthreads();
    if (tid == 0)
        atomicAdd(out, (red[0] + red[1] + red[2] + red[3]) * (1.f / N_ROWS));
}

extern "C" void kernel_launch(void* const* d_in, const int* in_sizes, int n_in,
                              void* d_out, int out_size, void* d_ws, size_t ws_size,
                              hipStream_t stream) {
    const float* feat = (const float*)d_in[0];
    char* ws = (char*)d_ws;
    unsigned short* fbf = (unsigned short*)ws;                 // 4 MB bf16
    float* sumexp = (float*)(ws + 4u * 1024u * 1024u);         // 32 KB

    k_norm<<<N_ROWS / 4, 256, 0, stream>>>(feat, fbf, sumexp, (float*)d_out);
    k_sim <<<512,        256, 0, stream>>>(fbf, sumexp);
    k_nll <<<N_ROWS / 4, 256, 0, stream>>>(feat, sumexp, (float*)d_out);
}